// Round 8
// baseline (340.256 us; speedup 1.0000x reference)
//
#include <hip/hip_runtime.h>

#define IMG_H 512
#define IMG_W 512
#define TILE_W 64
#define TILE_H 16
#define TCOLS 72
#define TROWS 16
#define NSLOTA (TROWS * (TCOLS / 4))   // 288 f4 slots per T plane
#define NTHREADS 256

// ---------------- compile-time coefficient generation --------------------
// Verbatim from the R7-VERIFIED two-phase separable kernel (passed, absmax
// 0.00390625).

constexpr double PI_D = 3.141592653589793238462643383279502884;

constexpr double cexp(double x) {
  double term = 1.0, sum = 1.0;
  for (int n = 1; n < 48; ++n) { term *= x / n; sum += term; }
  return sum;
}
constexpr double ccos(double x) {
  double term = 1.0, sum = 1.0;
  for (int n = 1; n < 24; ++n) {
    term *= -x * x / ((2.0 * n - 1.0) * (2.0 * n));
    sum += term;
  }
  return sum;
}
constexpr double csin(double x) {
  double term = x, sum = x;
  for (int n = 1; n < 24; ++n) {
    term *= -x * x / ((2.0 * n) * (2.0 * n + 1.0));
    sum += term;
  }
  return sum;
}
constexpr double cabs_(double x) { return x < 0 ? -x : x; }

constexpr void fill_log(int ks, double sigma, float* out) {
  double buf[49] = {};
  double s = 0.0;
  const int h = ks / 2;
  for (int i = 0; i < ks; ++i) {
    for (int j = 0; j < ks; ++j) {
      const double xi = (double)(i - h);
      const double yj = (double)(j - h);
      const double r2 = xi * xi + yj * yj;
      const double g = cexp(-r2 / (2.0 * sigma * sigma));
      const double lap = -1.0 / (PI_D * sigma * sigma * sigma * sigma) *
                         (1.0 - r2 / (2.0 * sigma * sigma));
      buf[i * ks + j] = lap * g;
      s += cabs_(lap * g);
    }
  }
  for (int k = 0; k < ks * ks; ++k) out[k] = (float)(buf[k] / s);
}

constexpr void fill_log_sep(int ks, double sigma, float* va, float* g, float* wb) {
  const int h = ks / 2;
  double s = 0.0;
  for (int i = 0; i < ks; ++i)
    for (int j = 0; j < ks; ++j) {
      const double xi = (double)(i - h), yj = (double)(j - h);
      const double r2 = xi * xi + yj * yj;
      const double gg = cexp(-r2 / (2.0 * sigma * sigma));
      const double lap = -1.0 / (PI_D * sigma * sigma * sigma * sigma) *
                         (1.0 - r2 / (2.0 * sigma * sigma));
      s += cabs_(lap * gg);
    }
  const double c = 1.0 / (PI_D * sigma * sigma * sigma * sigma);
  for (int i = 0; i < ks; ++i) {
    const double d = (double)(i - h);
    const double gi = cexp(-d * d / (2.0 * sigma * sigma));
    g[i] = (float)gi;
    va[i] = (float)((-c + c * d * d / (2.0 * sigma * sigma)) * gi / s);
    wb[i] = (float)((c * d * d / (2.0 * sigma * sigma)) * gi / s);
  }
}

constexpr double gabor_norm(double ang_deg) {
  const double th = ang_deg * PI_D / 180.0;
  const double ct = ccos(th), st = csin(th);
  double s = 0.0;
  for (int i = 0; i < 7; ++i)
    for (int j = 0; j < 7; ++j) {
      const double xv = (double)(j - 3);
      const double yv = (double)(i - 3);
      const double xt = xv * ct + yv * st;
      const double yt = -xv * st + yv * ct;
      const double g = cexp(-(xt * xt / 4.0 + yt * yt / 4.0) / 2.0) *
                       ccos(2.0 * PI_D * 0.1 * xt);
      s += cabs_(g);
    }
  return s;
}

struct SepTabs {
  float l5_va[5], l5_g[5], l5_wb[5];
  float l7_va[7], l7_g[7], l7_wb[7];
  float v_gb[7], v_gc0[7], v_gca[7], v_gsa[7];
  float h_g0[7], h_g90[7], h_gc[7], h_gs[7];
  float is45, is135;
  float l3_m, l3_e, l3_s;
};

constexpr SepTabs make_sep() {
  SepTabs t{};
  fill_log_sep(5, 1.0, t.l5_va, t.l5_g, t.l5_wb);
  fill_log_sep(7, 1.4, t.l7_va, t.l7_g, t.l7_wb);
  const double s0 = gabor_norm(0.0), s90 = gabor_norm(90.0);
  const double s45 = gabor_norm(45.0), s135 = gabor_norm(135.0);
  const double th45 = 45.0 * PI_D / 180.0;
  const double a45 = 2.0 * PI_D * 0.1 * ccos(th45);
  const double b45 = 2.0 * PI_D * 0.1 * csin(th45);
  const double w0 = 2.0 * PI_D * 0.1;
  for (int k = 0; k < 7; ++k) {
    const double d = (double)(k - 3);
    const double gg = cexp(-d * d / 8.0);
    t.v_gb[k]  = (float)gg;
    t.v_gc0[k] = (float)(gg * ccos(w0 * d));
    t.v_gca[k] = (float)(gg * ccos(b45 * d));
    t.v_gsa[k] = (float)(gg * csin(b45 * d));
    t.h_g0[k]  = (float)(gg * ccos(w0 * d) / s0);
    t.h_g90[k] = (float)(gg / s90);
    t.h_gc[k]  = (float)(gg * ccos(a45 * d));
    t.h_gs[k]  = (float)(gg * csin(a45 * d));
  }
  t.is45 = (float)(1.0 / s45);
  t.is135 = (float)(1.0 / s135);
  float l3[9] = {};
  fill_log(3, 0.8, l3);
  t.l3_m = l3[4]; t.l3_e = l3[1]; t.l3_s = l3[0];
  return t;
}

constexpr SepTabs ST = make_sep();

// ------------------------------- helpers ---------------------------------

__device__ __forceinline__ float fast_tanh(float x) {
  float e = __builtin_amdgcn_exp2f(x * 2.8853900817779268f);
  return 1.0f - 2.0f * __builtin_amdgcn_rcpf(e + 1.0f);
}
__device__ __forceinline__ float squash_from(float z) {
  return fmaf(fast_tanh(0.1f * z), 0.5f, 0.5f);
}
__device__ __forceinline__ float4 f4z() { return make_float4(0.f, 0.f, 0.f, 0.f); }
__device__ __forceinline__ float4 f4add(float4 a, float4 b) {
  return make_float4(a.x + b.x, a.y + b.y, a.z + b.z, a.w + b.w);
}
__device__ __forceinline__ float4 f4fma(float a, float4 b, float4 c) {
  return make_float4(fmaf(a, b.x, c.x), fmaf(a, b.y, c.y),
                     fmaf(a, b.z, c.z), fmaf(a, b.w, c.w));
}
__device__ __forceinline__ void loadw12(const float* p, float* w) {
  const float4 a = *(const float4*)(p);
  const float4 b = *(const float4*)(p + 4);
  const float4 c = *(const float4*)(p + 8);
  w[0] = a.x; w[1] = a.y; w[2] = a.z; w[3] = a.w;
  w[4] = b.x; w[5] = b.y; w[6] = b.z; w[7] = b.w;
  w[8] = c.x; w[9] = c.y; w[10] = c.z; w[11] = c.w;
}
// Guarded global float4 load. All callers pass 16B-aligned addresses whose
// 4 floats are full-in or full-out of the image row (gx multiple of 4,
// IMG_W=512 multiple of 4) -> single range check, zero-fill matches the
// reference conv's zero padding.
__device__ __forceinline__ float4 gload(const float* __restrict__ p, bool ok) {
  float4 v = make_float4(0.f, 0.f, 0.f, 0.f);
  if (ok) v = *(const float4*)p;
  return v;
}

// ------------------------------- kernel ----------------------------------
// Two-phase separable WITHOUT an LDS input tile: vertical passes and the
// 3x3 read input directly from global (per-block footprint 6.3 KB ->
// L1-resident; halo re-reads L2-served). LDS = 5 T-planes = 23,040 B ->
// 6 blocks/CU. ds-instructions/thread drop ~63 -> ~37 (the R7 pipe model's
// largest term), barriers 4 -> 3.

__global__ __launch_bounds__(NTHREADS, 6)
void msif_kernel(const float* __restrict__ x, float* __restrict__ out,
                 int planes, int do_gab) {
  __shared__ float T[5][TROWS * TCOLS];    // 23040 B (reused A then B)

  const int tid = threadIdx.x;
  const int tx = tid & 15;
  const int ty = tid >> 4;
  const int x0 = blockIdx.x * TILE_W;
  const int y0 = blockIdx.y * TILE_H;
  const int plane = blockIdx.z;
  const float* __restrict__ in = x + (size_t)plane * (IMG_H * IMG_W);

  // ---- phase A vertical: B5, L5A, L5G, L7A, L7G (global -> T) ----
  for (int k = tid; k < NSLOTA; k += NTHREADS) {
    const int r = k / (TCOLS / 4);
    const int c4 = (k - r * (TCOLS / 4)) * 4;
    const int gx = x0 - 4 + c4;
    const bool xok = (unsigned)gx <= (unsigned)(IMG_W - 4);
    const int gyb = y0 - 3 + r;
    float4 wv[7];
#pragma unroll
    for (int i = 0; i < 7; ++i) {
      const int gy = gyb + i;
      wv[i] = gload(in + (size_t)gy * IMG_W + gx,
                    xok && (unsigned)gy < IMG_H);
    }

    float4 b5 = f4add(f4add(wv[1], wv[2]), f4add(f4add(wv[3], wv[4]), wv[5]));
    float4 l5a = f4z(), l5g = f4z();
#pragma unroll
    for (int i = 0; i < 5; ++i) {
      l5a = f4fma(ST.l5_va[i], wv[i + 1], l5a);
      l5g = f4fma(ST.l5_g[i],  wv[i + 1], l5g);
    }
    float4 l7a = f4z(), l7g = f4z();
#pragma unroll
    for (int i = 0; i < 7; ++i) {
      l7a = f4fma(ST.l7_va[i], wv[i], l7a);
      l7g = f4fma(ST.l7_g[i],  wv[i], l7g);
    }
    const int o = r * TCOLS + c4;
    *(float4*)&T[0][o] = b5;
    *(float4*)&T[1][o] = l5a;
    *(float4*)&T[2][o] = l5g;
    *(float4*)&T[3][o] = l7a;
    *(float4*)&T[4][o] = l7g;
  }
  __syncthreads();

  const size_t fs = (size_t)planes * (IMG_H * IMG_W);
  const size_t off = (size_t)plane * (IMG_H * IMG_W) +
                     (size_t)(y0 + ty) * IMG_W + (x0 + 4 * tx);
  const int toff = ty * TCOLS + 4 * tx;

  // ---- phase A horizontal + 3x3 (global) + stores ----
  {
    float w[12];
    float l7[4] = {}, l5[4] = {}, box[4];

    loadw12(&T[3][toff], w);               // L7A * g
#pragma unroll
    for (int dx = 0; dx < 7; ++dx) {
      const float cc = ST.l7_g[dx];
#pragma unroll
      for (int c = 0; c < 4; ++c) l7[c] = fmaf(w[c + dx + 1], cc, l7[c]);
    }
    loadw12(&T[4][toff], w);               // L7G * wb
#pragma unroll
    for (int dx = 0; dx < 7; ++dx) {
      const float cc = ST.l7_wb[dx];
#pragma unroll
      for (int c = 0; c < 4; ++c) l7[c] = fmaf(w[c + dx + 1], cc, l7[c]);
    }
    loadw12(&T[1][toff], w);               // L5A * g
#pragma unroll
    for (int dx = 0; dx < 5; ++dx) {
      const float cc = ST.l5_g[dx];
#pragma unroll
      for (int c = 0; c < 4; ++c) l5[c] = fmaf(w[c + dx + 2], cc, l5[c]);
    }
    loadw12(&T[2][toff], w);               // L5G * wb
#pragma unroll
    for (int dx = 0; dx < 5; ++dx) {
      const float cc = ST.l5_wb[dx];
#pragma unroll
      for (int c = 0; c < 4; ++c) l5[c] = fmaf(w[c + dx + 2], cc, l5[c]);
    }
    loadw12(&T[0][toff], w);               // B5 horizontal box
#pragma unroll
    for (int c = 0; c < 4; ++c)
      box[c] = ((w[c + 2] + w[c + 3]) + (w[c + 4] + w[c + 5])) + w[c + 6];

    // 3x3 class sums from GLOBAL rows y0+ty-1 .. y0+ty+1, cols x0+4tx-4..+7
    const int gxr = x0 + 4 * tx - 4;
    const int gyc = y0 + ty;
    float m[4], e[4], s[4];
    {
      const int gy = gyc - 1;
      const bool yok = (unsigned)gy < IMG_H;
      const float* rp = in + (size_t)gy * IMG_W;
#pragma unroll
      for (int j = 0; j < 3; ++j) {
        const float4 v = gload(rp + gxr + 4 * j,
                               yok && (unsigned)(gxr + 4 * j) <= (unsigned)(IMG_W - 4));
        w[4 * j + 0] = v.x; w[4 * j + 1] = v.y; w[4 * j + 2] = v.z; w[4 * j + 3] = v.w;
      }
#pragma unroll
      for (int c = 0; c < 4; ++c) {
        e[c] = w[c + 4];
        s[c] = w[c + 3] + w[c + 5];
      }
    }
    {
      const int gy = gyc + 1;
      const bool yok = (unsigned)gy < IMG_H;
      const float* rp = in + (size_t)gy * IMG_W;
#pragma unroll
      for (int j = 0; j < 3; ++j) {
        const float4 v = gload(rp + gxr + 4 * j,
                               yok && (unsigned)(gxr + 4 * j) <= (unsigned)(IMG_W - 4));
        w[4 * j + 0] = v.x; w[4 * j + 1] = v.y; w[4 * j + 2] = v.z; w[4 * j + 3] = v.w;
      }
#pragma unroll
      for (int c = 0; c < 4; ++c) {
        e[c] += w[c + 4];
        s[c] += w[c + 3] + w[c + 5];
      }
    }
    {
      const float* rp = in + (size_t)gyc * IMG_W;   // center row always valid
#pragma unroll
      for (int j = 0; j < 3; ++j) {
        const float4 v = gload(rp + gxr + 4 * j,
                               (unsigned)(gxr + 4 * j) <= (unsigned)(IMG_W - 4));
        w[4 * j + 0] = v.x; w[4 * j + 1] = v.y; w[4 * j + 2] = v.z; w[4 * j + 3] = v.w;
      }
      *(float4*)(out + off) = make_float4(w[4], w[5], w[6], w[7]);  // original
#pragma unroll
      for (int c = 0; c < 4; ++c) {
        m[c] = w[c + 4];
        e[c] += w[c + 3] + w[c + 5];
      }
    }

    float lp[4], lo[4], ho[4];
#pragma unroll
    for (int c = 0; c < 4; ++c) {
      lp[c] = fmaf(0.25f, m[c], fmaf(0.125f, e[c], 0.0625f * s[c]));
      const float l3v = fmaf(ST.l3_m, m[c], fmaf(ST.l3_e, e[c], ST.l3_s * s[c]));
      const float h3v = fmaf(8.f, m[c], -(e[c] + s[c]));
      const float h5v = fmaf(25.f, m[c], -box[c]);
      lo[c] = squash_from(fmaxf(fmaxf(l3v, l5[c]), l7[c]));
      ho[c] = squash_from(fmaxf(h3v, h5v));
    }
    *(float4*)(out + fs + off) = make_float4(lp[0], lp[1], lp[2], lp[3]);
    *(float4*)(out + 2 * fs + off) = make_float4(lo[0], lo[1], lo[2], lo[3]);
    *(float4*)(out + 3 * fs + off) = make_float4(ho[0], ho[1], ho[2], ho[3]);
  }

  if (!do_gab) return;
  __syncthreads();   // all T reads of phase A done before overwrite

  // ---- phase B vertical: GB, GC0, GCA, GSA (global L1-hit -> T) ----
  for (int k = tid; k < NSLOTA; k += NTHREADS) {
    const int r = k / (TCOLS / 4);
    const int c4 = (k - r * (TCOLS / 4)) * 4;
    const int gx = x0 - 4 + c4;
    const bool xok = (unsigned)gx <= (unsigned)(IMG_W - 4);
    const int gyb = y0 - 3 + r;
    float4 gb = f4z(), gc0 = f4z(), gca = f4z(), gsa = f4z();
#pragma unroll
    for (int i = 0; i < 7; ++i) {
      const int gy = gyb + i;
      const float4 wv = gload(in + (size_t)gy * IMG_W + gx,
                              xok && (unsigned)gy < IMG_H);
      gb  = f4fma(ST.v_gb[i],  wv, gb);
      gc0 = f4fma(ST.v_gc0[i], wv, gc0);
      gca = f4fma(ST.v_gca[i], wv, gca);
      gsa = f4fma(ST.v_gsa[i], wv, gsa);
    }
    const int o = r * TCOLS + c4;
    *(float4*)&T[0][o] = gb;
    *(float4*)&T[1][o] = gc0;
    *(float4*)&T[2][o] = gca;
    *(float4*)&T[3][o] = gsa;
  }
  __syncthreads();

  // ---- phase B horizontal + store (gabor) ----
  {
    float w[12];
    float g0[4] = {}, g90[4] = {}, Pa[4] = {}, Qa[4] = {};

    loadw12(&T[0][toff], w);
#pragma unroll
    for (int dx = 0; dx < 7; ++dx) {
      const float cc = ST.h_g0[dx];
#pragma unroll
      for (int c = 0; c < 4; ++c) g0[c] = fmaf(w[c + dx + 1], cc, g0[c]);
    }
    loadw12(&T[1][toff], w);
#pragma unroll
    for (int dx = 0; dx < 7; ++dx) {
      const float cc = ST.h_g90[dx];
#pragma unroll
      for (int c = 0; c < 4; ++c) g90[c] = fmaf(w[c + dx + 1], cc, g90[c]);
    }
    loadw12(&T[2][toff], w);
#pragma unroll
    for (int dx = 0; dx < 7; ++dx) {
      const float cc = ST.h_gc[dx];
#pragma unroll
      for (int c = 0; c < 4; ++c) Pa[c] = fmaf(w[c + dx + 1], cc, Pa[c]);
    }
    loadw12(&T[3][toff], w);
#pragma unroll
    for (int dx = 0; dx < 7; ++dx) {
      const float cc = ST.h_gs[dx];
#pragma unroll
      for (int c = 0; c < 4; ++c) Qa[c] = fmaf(w[c + dx + 1], cc, Qa[c]);
    }

    float go[4];
#pragma unroll
    for (int c = 0; c < 4; ++c) {
      const float o45  = (Pa[c] - Qa[c]) * ST.is45;
      const float o135 = (Pa[c] + Qa[c]) * ST.is135;
      go[c] = fast_tanh(0.1f * fmaxf(fmaxf(g0[c], g90[c]), fmaxf(o45, o135)));
    }
    *(float4*)(out + 4 * fs + off) = make_float4(go[0], go[1], go[2], go[3]);
  }
}

extern "C" void kernel_launch(void* const* d_in, const int* in_sizes, int n_in,
                              void* d_out, int out_size, void* d_ws, size_t ws_size,
                              hipStream_t stream) {
  const float* x = (const float*)d_in[0];
  float* out = (float*)d_out;
  const int plane_elems = IMG_H * IMG_W;
  const int planes = in_sizes[0] / plane_elems;               // 16*3 = 48
  const int do_gab = (out_size >= 5 * in_sizes[0]) ? 1 : 0;

  dim3 grid(IMG_W / TILE_W, IMG_H / TILE_H, planes);
  msif_kernel<<<grid, NTHREADS, 0, stream>>>(x, out, planes, do_gab);
}

// Round 9
// 309.585 us; speedup vs baseline: 1.0991x; 1.0991x over previous
//
#include <hip/hip_runtime.h>

#define IMG_H 512
#define IMG_W 512
#define TILE_W 64
#define TILE_H 16
#define LDSW 72   // 64 + 8 halo/alignment cols
#define LDSH 22   // 16 + 6 halo rows
#define TCOLS 72
#define TROWS 16
#define NSLOTA (TROWS * (TCOLS / 4))   // 288 f4 slots per T plane
#define NTHREADS 256

// ---------------- compile-time coefficient generation --------------------
// Verbatim from the R7-VERIFIED two-phase separable kernel (passed, absmax
// 0.00390625).

constexpr double PI_D = 3.141592653589793238462643383279502884;

constexpr double cexp(double x) {
  double term = 1.0, sum = 1.0;
  for (int n = 1; n < 48; ++n) { term *= x / n; sum += term; }
  return sum;
}
constexpr double ccos(double x) {
  double term = 1.0, sum = 1.0;
  for (int n = 1; n < 24; ++n) {
    term *= -x * x / ((2.0 * n - 1.0) * (2.0 * n));
    sum += term;
  }
  return sum;
}
constexpr double csin(double x) {
  double term = x, sum = x;
  for (int n = 1; n < 24; ++n) {
    term *= -x * x / ((2.0 * n) * (2.0 * n + 1.0));
    sum += term;
  }
  return sum;
}
constexpr double cabs_(double x) { return x < 0 ? -x : x; }

constexpr void fill_log(int ks, double sigma, float* out) {
  double buf[49] = {};
  double s = 0.0;
  const int h = ks / 2;
  for (int i = 0; i < ks; ++i) {
    for (int j = 0; j < ks; ++j) {
      const double xi = (double)(i - h);
      const double yj = (double)(j - h);
      const double r2 = xi * xi + yj * yj;
      const double g = cexp(-r2 / (2.0 * sigma * sigma));
      const double lap = -1.0 / (PI_D * sigma * sigma * sigma * sigma) *
                         (1.0 - r2 / (2.0 * sigma * sigma));
      buf[i * ks + j] = lap * g;
      s += cabs_(lap * g);
    }
  }
  for (int k = 0; k < ks * ks; ++k) out[k] = (float)(buf[k] / s);
}

constexpr void fill_log_sep(int ks, double sigma, float* va, float* g, float* wb) {
  const int h = ks / 2;
  double s = 0.0;
  for (int i = 0; i < ks; ++i)
    for (int j = 0; j < ks; ++j) {
      const double xi = (double)(i - h), yj = (double)(j - h);
      const double r2 = xi * xi + yj * yj;
      const double gg = cexp(-r2 / (2.0 * sigma * sigma));
      const double lap = -1.0 / (PI_D * sigma * sigma * sigma * sigma) *
                         (1.0 - r2 / (2.0 * sigma * sigma));
      s += cabs_(lap * gg);
    }
  const double c = 1.0 / (PI_D * sigma * sigma * sigma * sigma);
  for (int i = 0; i < ks; ++i) {
    const double d = (double)(i - h);
    const double gi = cexp(-d * d / (2.0 * sigma * sigma));
    g[i] = (float)gi;
    va[i] = (float)((-c + c * d * d / (2.0 * sigma * sigma)) * gi / s);
    wb[i] = (float)((c * d * d / (2.0 * sigma * sigma)) * gi / s);
  }
}

constexpr double gabor_norm(double ang_deg) {
  const double th = ang_deg * PI_D / 180.0;
  const double ct = ccos(th), st = csin(th);
  double s = 0.0;
  for (int i = 0; i < 7; ++i)
    for (int j = 0; j < 7; ++j) {
      const double xv = (double)(j - 3);
      const double yv = (double)(i - 3);
      const double xt = xv * ct + yv * st;
      const double yt = -xv * st + yv * ct;
      const double g = cexp(-(xt * xt / 4.0 + yt * yt / 4.0) / 2.0) *
                       ccos(2.0 * PI_D * 0.1 * xt);
      s += cabs_(g);
    }
  return s;
}

struct SepTabs {
  float l5_va[5], l5_g[5], l5_wb[5];
  float l7_va[7], l7_g[7], l7_wb[7];
  float v_gb[7], v_gc0[7], v_gca[7], v_gsa[7];
  float h_g0[7], h_g90[7], h_gc[7], h_gs[7];
  float is45, is135;
  float l3_m, l3_e, l3_s;
};

constexpr SepTabs make_sep() {
  SepTabs t{};
  fill_log_sep(5, 1.0, t.l5_va, t.l5_g, t.l5_wb);
  fill_log_sep(7, 1.4, t.l7_va, t.l7_g, t.l7_wb);
  const double s0 = gabor_norm(0.0), s90 = gabor_norm(90.0);
  const double s45 = gabor_norm(45.0), s135 = gabor_norm(135.0);
  const double th45 = 45.0 * PI_D / 180.0;
  const double a45 = 2.0 * PI_D * 0.1 * ccos(th45);
  const double b45 = 2.0 * PI_D * 0.1 * csin(th45);
  const double w0 = 2.0 * PI_D * 0.1;
  for (int k = 0; k < 7; ++k) {
    const double d = (double)(k - 3);
    const double gg = cexp(-d * d / 8.0);
    t.v_gb[k]  = (float)gg;
    t.v_gc0[k] = (float)(gg * ccos(w0 * d));
    t.v_gca[k] = (float)(gg * ccos(b45 * d));
    t.v_gsa[k] = (float)(gg * csin(b45 * d));
    t.h_g0[k]  = (float)(gg * ccos(w0 * d) / s0);
    t.h_g90[k] = (float)(gg / s90);
    t.h_gc[k]  = (float)(gg * ccos(a45 * d));
    t.h_gs[k]  = (float)(gg * csin(a45 * d));
  }
  t.is45 = (float)(1.0 / s45);
  t.is135 = (float)(1.0 / s135);
  float l3[9] = {};
  fill_log(3, 0.8, l3);
  t.l3_m = l3[4]; t.l3_e = l3[1]; t.l3_s = l3[0];
  return t;
}

constexpr SepTabs ST = make_sep();

// ------------------------------- helpers ---------------------------------

__device__ __forceinline__ float fast_tanh(float x) {
  float e = __builtin_amdgcn_exp2f(x * 2.8853900817779268f);
  return 1.0f - 2.0f * __builtin_amdgcn_rcpf(e + 1.0f);
}
__device__ __forceinline__ float squash_from(float z) {
  return fmaf(fast_tanh(0.1f * z), 0.5f, 0.5f);
}
__device__ __forceinline__ float4 f4z() { return make_float4(0.f, 0.f, 0.f, 0.f); }
__device__ __forceinline__ float4 f4fma(float a, float4 b, float4 c) {
  return make_float4(fmaf(a, b.x, c.x), fmaf(a, b.y, c.y),
                     fmaf(a, b.z, c.z), fmaf(a, b.w, c.w));
}
__device__ __forceinline__ void loadw12(const float* p, float* w) {
  const float4 a = *(const float4*)(p);
  const float4 b = *(const float4*)(p + 4);
  const float4 c = *(const float4*)(p + 8);
  w[0] = a.x; w[1] = a.y; w[2] = a.z; w[3] = a.w;
  w[4] = b.x; w[5] = b.y; w[6] = b.z; w[7] = b.w;
  w[8] = c.x; w[9] = c.y; w[10] = c.z; w[11] = c.w;
}

// ------------------------------- kernel ----------------------------------
// R7 structure with the B5 plane removed: T has 4 planes (reused A then B);
// the hpf5 vertical box is recomputed in A-horiz from the input tile, fused
// with the 3x3 class-sum pass (which shares 3 of its 5 row reads).
// LDS = 6336 (tile) + 18432 (T) = 24768 B -> 6 blocks/CU (was 5).

__global__ __launch_bounds__(NTHREADS, 6)
void msif_kernel(const float* __restrict__ x, float* __restrict__ out,
                 int planes, int do_gab) {
  __shared__ float tile[LDSH * LDSW];      // 6336 B
  __shared__ float T[4][TROWS * TCOLS];    // 18432 B (reused A then B)

  const int tid = threadIdx.x;
  const int tx = tid & 15;
  const int ty = tid >> 4;
  const int x0 = blockIdx.x * TILE_W;
  const int y0 = blockIdx.y * TILE_H;
  const int plane = blockIdx.z;
  const float* __restrict__ in = x + (size_t)plane * (IMG_H * IMG_W);

  // ---- stage input tile (verbatim R0/R7) ----
  const int gx0 = x0 - 4;
  const int gy0 = y0 - 3;
  for (int k = tid; k < LDSH * (LDSW / 4); k += NTHREADS) {
    int r = k / (LDSW / 4);
    int cc = (k - r * (LDSW / 4)) * 4;
    int gy = gy0 + r;
    int gx = gx0 + cc;
    float4 v = make_float4(0.f, 0.f, 0.f, 0.f);
    if ((unsigned)gy < IMG_H) {
      const float* rowp = in + (size_t)gy * IMG_W;
      if (gx >= 0 && gx + 3 < IMG_W) {
        v = *(const float4*)(rowp + gx);
      } else {
        if ((unsigned)(gx + 0) < IMG_W) v.x = rowp[gx + 0];
        if ((unsigned)(gx + 1) < IMG_W) v.y = rowp[gx + 1];
        if ((unsigned)(gx + 2) < IMG_W) v.z = rowp[gx + 2];
        if ((unsigned)(gx + 3) < IMG_W) v.w = rowp[gx + 3];
      }
    }
    *(float4*)&tile[r * LDSW + cc] = v;
  }
  __syncthreads();

  // ---- phase A vertical: L5A, L5G, L7A, L7G ----
  for (int k = tid; k < NSLOTA; k += NTHREADS) {
    const int r = k / (TCOLS / 4);
    const int c4 = (k - r * (TCOLS / 4)) * 4;
    const float* base = &tile[r * LDSW + c4];
    float4 wv[7];
#pragma unroll
    for (int i = 0; i < 7; ++i) wv[i] = *(const float4*)(base + i * LDSW);

    float4 l5a = f4z(), l5g = f4z();
#pragma unroll
    for (int i = 0; i < 5; ++i) {
      l5a = f4fma(ST.l5_va[i], wv[i + 1], l5a);
      l5g = f4fma(ST.l5_g[i],  wv[i + 1], l5g);
    }
    float4 l7a = f4z(), l7g = f4z();
#pragma unroll
    for (int i = 0; i < 7; ++i) {
      l7a = f4fma(ST.l7_va[i], wv[i], l7a);
      l7g = f4fma(ST.l7_g[i],  wv[i], l7g);
    }
    const int o = r * TCOLS + c4;
    *(float4*)&T[0][o] = l5a;
    *(float4*)&T[1][o] = l5g;
    *(float4*)&T[2][o] = l7a;
    *(float4*)&T[3][o] = l7g;
  }
  __syncthreads();

  const size_t fs = (size_t)planes * (IMG_H * IMG_W);
  const size_t off = (size_t)plane * (IMG_H * IMG_W) +
                     (size_t)(y0 + ty) * IMG_W + (x0 + 4 * tx);
  const int toff = ty * TCOLS + 4 * tx;

  // ---- phase A horizontal + fused tile pass (box5v + 3x3) + stores ----
  {
    float w[12];
    float l7[4] = {}, l5[4] = {};

    loadw12(&T[2][toff], w);               // L7A * g
#pragma unroll
    for (int dx = 0; dx < 7; ++dx) {
      const float cc = ST.l7_g[dx];
#pragma unroll
      for (int c = 0; c < 4; ++c) l7[c] = fmaf(w[c + dx + 1], cc, l7[c]);
    }
    loadw12(&T[3][toff], w);               // L7G * wb
#pragma unroll
    for (int dx = 0; dx < 7; ++dx) {
      const float cc = ST.l7_wb[dx];
#pragma unroll
      for (int c = 0; c < 4; ++c) l7[c] = fmaf(w[c + dx + 1], cc, l7[c]);
    }
    loadw12(&T[0][toff], w);               // L5A * g
#pragma unroll
    for (int dx = 0; dx < 5; ++dx) {
      const float cc = ST.l5_g[dx];
#pragma unroll
      for (int c = 0; c < 4; ++c) l5[c] = fmaf(w[c + dx + 2], cc, l5[c]);
    }
    loadw12(&T[1][toff], w);               // L5G * wb
#pragma unroll
    for (int dx = 0; dx < 5; ++dx) {
      const float cc = ST.l5_wb[dx];
#pragma unroll
      for (int c = 0; c < 4; ++c) l5[c] = fmaf(w[c + dx + 2], cc, l5[c]);
    }

    // fused tile pass: rows ty+1..ty+5 -> vertical box5 (vb) + 3x3 sums
    float vb[12], m[4], e[4], s[4];
    loadw12(&tile[(ty + 1) * LDSW + 4 * tx], w);          // row -2
#pragma unroll
    for (int q = 0; q < 12; ++q) vb[q] = w[q];
    loadw12(&tile[(ty + 2) * LDSW + 4 * tx], w);          // row -1 (3x3 top)
#pragma unroll
    for (int q = 0; q < 12; ++q) vb[q] += w[q];
#pragma unroll
    for (int c = 0; c < 4; ++c) {
      e[c] = w[c + 4];
      s[c] = w[c + 3] + w[c + 5];
    }
    loadw12(&tile[(ty + 3) * LDSW + 4 * tx], w);          // row 0 (center)
    *(float4*)(out + off) = make_float4(w[4], w[5], w[6], w[7]);  // original
#pragma unroll
    for (int q = 0; q < 12; ++q) vb[q] += w[q];
#pragma unroll
    for (int c = 0; c < 4; ++c) {
      m[c] = w[c + 4];
      e[c] += w[c + 3] + w[c + 5];
    }
    loadw12(&tile[(ty + 4) * LDSW + 4 * tx], w);          // row +1 (3x3 bot)
#pragma unroll
    for (int q = 0; q < 12; ++q) vb[q] += w[q];
#pragma unroll
    for (int c = 0; c < 4; ++c) {
      e[c] += w[c + 4];
      s[c] += w[c + 3] + w[c + 5];
    }
    loadw12(&tile[(ty + 5) * LDSW + 4 * tx], w);          // row +2
#pragma unroll
    for (int q = 0; q < 12; ++q) vb[q] += w[q];

    float lp[4], lo[4], ho[4];
#pragma unroll
    for (int c = 0; c < 4; ++c) {
      const float box =
          ((vb[c + 2] + vb[c + 3]) + (vb[c + 4] + vb[c + 5])) + vb[c + 6];
      lp[c] = fmaf(0.25f, m[c], fmaf(0.125f, e[c], 0.0625f * s[c]));
      const float l3v = fmaf(ST.l3_m, m[c], fmaf(ST.l3_e, e[c], ST.l3_s * s[c]));
      const float h3v = fmaf(8.f, m[c], -(e[c] + s[c]));
      const float h5v = fmaf(25.f, m[c], -box);
      lo[c] = squash_from(fmaxf(fmaxf(l3v, l5[c]), l7[c]));
      ho[c] = squash_from(fmaxf(h3v, h5v));
    }
    *(float4*)(out + fs + off) = make_float4(lp[0], lp[1], lp[2], lp[3]);
    *(float4*)(out + 2 * fs + off) = make_float4(lo[0], lo[1], lo[2], lo[3]);
    *(float4*)(out + 3 * fs + off) = make_float4(ho[0], ho[1], ho[2], ho[3]);
  }

  if (!do_gab) return;
  __syncthreads();   // all T reads of phase A done before overwrite

  // ---- phase B vertical: GB, GC0, GCA, GSA into reused T ----
  for (int k = tid; k < NSLOTA; k += NTHREADS) {
    const int r = k / (TCOLS / 4);
    const int c4 = (k - r * (TCOLS / 4)) * 4;
    const float* base = &tile[r * LDSW + c4];
    float4 gb = f4z(), gc0 = f4z(), gca = f4z(), gsa = f4z();
#pragma unroll
    for (int i = 0; i < 7; ++i) {
      const float4 wv = *(const float4*)(base + i * LDSW);
      gb  = f4fma(ST.v_gb[i],  wv, gb);
      gc0 = f4fma(ST.v_gc0[i], wv, gc0);
      gca = f4fma(ST.v_gca[i], wv, gca);
      gsa = f4fma(ST.v_gsa[i], wv, gsa);
    }
    const int o = r * TCOLS + c4;
    *(float4*)&T[0][o] = gb;
    *(float4*)&T[1][o] = gc0;
    *(float4*)&T[2][o] = gca;
    *(float4*)&T[3][o] = gsa;
  }
  __syncthreads();

  // ---- phase B horizontal + store (gabor) ----
  {
    float w[12];
    float g0[4] = {}, g90[4] = {}, Pa[4] = {}, Qa[4] = {};

    loadw12(&T[0][toff], w);
#pragma unroll
    for (int dx = 0; dx < 7; ++dx) {
      const float cc = ST.h_g0[dx];
#pragma unroll
      for (int c = 0; c < 4; ++c) g0[c] = fmaf(w[c + dx + 1], cc, g0[c]);
    }
    loadw12(&T[1][toff], w);
#pragma unroll
    for (int dx = 0; dx < 7; ++dx) {
      const float cc = ST.h_g90[dx];
#pragma unroll
      for (int c = 0; c < 4; ++c) g90[c] = fmaf(w[c + dx + 1], cc, g90[c]);
    }
    loadw12(&T[2][toff], w);
#pragma unroll
    for (int dx = 0; dx < 7; ++dx) {
      const float cc = ST.h_gc[dx];
#pragma unroll
      for (int c = 0; c < 4; ++c) Pa[c] = fmaf(w[c + dx + 1], cc, Pa[c]);
    }
    loadw12(&T[3][toff], w);
#pragma unroll
    for (int dx = 0; dx < 7; ++dx) {
      const float cc = ST.h_gs[dx];
#pragma unroll
      for (int c = 0; c < 4; ++c) Qa[c] = fmaf(w[c + dx + 1], cc, Qa[c]);
    }

    float go[4];
#pragma unroll
    for (int c = 0; c < 4; ++c) {
      const float o45  = (Pa[c] - Qa[c]) * ST.is45;
      const float o135 = (Pa[c] + Qa[c]) * ST.is135;
      go[c] = fast_tanh(0.1f * fmaxf(fmaxf(g0[c], g90[c]), fmaxf(o45, o135)));
    }
    *(float4*)(out + 4 * fs + off) = make_float4(go[0], go[1], go[2], go[3]);
  }
}

extern "C" void kernel_launch(void* const* d_in, const int* in_sizes, int n_in,
                              void* d_out, int out_size, void* d_ws, size_t ws_size,
                              hipStream_t stream) {
  const float* x = (const float*)d_in[0];
  float* out = (float*)d_out;
  const int plane_elems = IMG_H * IMG_W;
  const int planes = in_sizes[0] / plane_elems;               // 16*3 = 48
  const int do_gab = (out_size >= 5 * in_sizes[0]) ? 1 : 0;

  dim3 grid(IMG_W / TILE_W, IMG_H / TILE_H, planes);
  msif_kernel<<<grid, NTHREADS, 0, stream>>>(x, out, planes, do_gab);
}